// Round 3
// baseline (1184.821 us; speedup 1.0000x reference)
//
#include <hip/hip_runtime.h>
#include <cstdint>
#include <cstddef>

#define S_ROWS 4096
#define DIM 1024
#define NE 64
#define CAP 512
#define NEGV -1e9f

typedef float v4f __attribute__((ext_vector_type(4)));  // native vector: OK for nontemporal builtins

// ---------------- zero-fill d_out (1.07 GB) — structural write floor ----------------
__global__ __launch_bounds__(256) void zerofill(v4f* __restrict__ out4, long long n4,
                                                float* __restrict__ out, long long n) {
    long long i = (long long)blockIdx.x * blockDim.x + threadIdx.x;
    long long stride = (long long)gridDim.x * blockDim.x;
    v4f z = {0.f, 0.f, 0.f, 0.f};
    for (; i < n4; i += stride) __builtin_nontemporal_store(z, &out4[i]);
    if (blockIdx.x == 0 && threadIdx.x == 0) {
        for (long long j = n4 * 4; j < n; ++j) out[j] = 0.f;  // 1 tail element
    }
}

// ---------------- logits GEMM: L = X @ W^T ; 32-row tiles, grid (128,2) = 256 blocks ----------------
__global__ __launch_bounds__(256) void gemm64(const float* __restrict__ X1, const float* __restrict__ W1,
                                              const float* __restrict__ X2, const float* __restrict__ W2,
                                              float* __restrict__ L1, float* __restrict__ L2,
                                              float* __restrict__ Gg, int* __restrict__ Cg) {
    // zero the l_aux accumulators once (completes before gatek2 by stream order)
    if (blockIdx.x == 0 && blockIdx.y == 0 && threadIdx.x < NE) {
        Gg[threadIdx.x] = 0.f;
        Cg[threadIdx.x] = 0;
    }
    const float* __restrict__ X = blockIdx.y ? X2 : X1;
    const float* __restrict__ W = blockIdx.y ? W2 : W1;
    float* __restrict__ L = blockIdx.y ? L2 : L1;

    __shared__ float As[32][68];   // [row][k], +4 pad keeps 16B align, breaks bank stride
    __shared__ float Bs[64][68];   // [k][expert]

    const int tid = threadIdx.x;
    const int row0 = blockIdx.x * 32;
    const int tx = tid & 15;       // expert quad
    const int ty = tid >> 4;       // row pair (0..15)

    float acc[2][4] = {};

    for (int kk = 0; kk < DIM; kk += 64) {
        __syncthreads();
        // A tile: 32 rows x 64 cols, coalesced float4
        #pragma unroll
        for (int p = 0; p < 2; ++p) {
            int r  = (tid >> 4) + p * 16;
            int c4 = (tid & 15) * 4;
            float4 a = *(const float4*)&X[(size_t)(row0 + r) * DIM + kk + c4];
            *(float4*)&As[r][c4] = a;
        }
        // W tile: 64 experts x 64 cols, transposed into Bs[k][e]
        #pragma unroll
        for (int p = 0; p < 4; ++p) {
            int e  = (tid >> 4) + p * 16;
            int c4 = (tid & 15) * 4;
            float4 w = *(const float4*)&W[(size_t)e * DIM + kk + c4];
            Bs[c4 + 0][e] = w.x;
            Bs[c4 + 1][e] = w.y;
            Bs[c4 + 2][e] = w.z;
            Bs[c4 + 3][e] = w.w;
        }
        __syncthreads();
        #pragma unroll
        for (int k4 = 0; k4 < 64; k4 += 4) {
            float4 a[2], b[4];
            #pragma unroll
            for (int i = 0; i < 2; ++i) a[i] = *(float4*)&As[ty * 2 + i][k4];
            #pragma unroll
            for (int t = 0; t < 4; ++t) b[t] = *(float4*)&Bs[k4 + t][tx * 4];
            #pragma unroll
            for (int i = 0; i < 2; ++i) {
                acc[i][0] += a[i].x * b[0].x + a[i].y * b[1].x + a[i].z * b[2].x + a[i].w * b[3].x;
                acc[i][1] += a[i].x * b[0].y + a[i].y * b[1].y + a[i].z * b[2].y + a[i].w * b[3].y;
                acc[i][2] += a[i].x * b[0].z + a[i].y * b[1].z + a[i].z * b[2].z + a[i].w * b[3].z;
                acc[i][3] += a[i].x * b[0].w + a[i].y * b[1].w + a[i].z * b[2].w + a[i].w * b[3].w;
            }
        }
    }
    #pragma unroll
    for (int i = 0; i < 2; ++i) {
        float4 v; v.x = acc[i][0]; v.y = acc[i][1]; v.z = acc[i][2]; v.w = acc[i][3];
        *(float4*)&L[(size_t)(row0 + ty * 2 + i) * NE + tx * 4] = v;
    }
}

// ---------------- gating + fused l_aux accumulation: 256 blocks x 16 rows ----------------
__global__ __launch_bounds__(256) void gatek2(const float* __restrict__ L1, const float* __restrict__ L2,
                                              int* __restrict__ eidx, float* __restrict__ gval,
                                              float* __restrict__ Gg, int* __restrict__ Cg) {
    __shared__ float sG[4][NE];
    __shared__ int hist[NE];
    const int wid = threadIdx.x >> 6, lane = threadIdx.x & 63;
    if (threadIdx.x < NE) hist[threadIdx.x] = 0;
    __syncthreads();

    const int r0 = blockIdx.x * 16 + wid * 4;
    float gacc = 0.f;
    #pragma unroll
    for (int i = 0; i < 4; ++i) {
        const int r = r0 + i;
        float l1 = L1[(size_t)r * NE + lane];
        if (lane == 0) l1 = NEGV;            // group 0 excluded before softmax

        // rank under (value desc, index asc) -> top-16 set == jax.lax.top_k set
        int cnt = 0;
        #pragma unroll
        for (int j = 0; j < 64; ++j) {
            float vj = __shfl(l1, j);
            cnt += (vj > l1 || (vj == l1 && j < lane));
        }
        const bool sel = cnt < 16;

        float l2 = L2[(size_t)r * NE + lane];
        float ml = sel ? l2 : NEGV;

        float m = ml;
        #pragma unroll
        for (int o = 32; o; o >>= 1) m = fmaxf(m, __shfl_xor(m, o));
        float ex = expf(ml - m);             // unselected underflow to exact 0
        float sum = ex;
        #pragma unroll
        for (int o = 32; o; o >>= 1) sum += __shfl_xor(sum, o);
        float g = ex / sum;
        gacc += g;

        // argmax, lowest-index tie-break (softmax monotone -> matches ref exactly)
        float bg = g; int bi = lane;
        #pragma unroll
        for (int o = 32; o; o >>= 1) {
            float og = __shfl_xor(bg, o);
            int   oi = __shfl_xor(bi, o);
            if (og > bg || (og == bg && oi < bi)) { bg = og; bi = oi; }
        }
        if (lane == 0) {
            eidx[r] = bi;
            gval[r] = bg;
            atomicAdd(&hist[bi], 1);
        }
    }
    sG[wid][lane] = gacc;
    __syncthreads();
    if (threadIdx.x < NE) {
        float g4 = sG[0][threadIdx.x] + sG[1][threadIdx.x] + sG[2][threadIdx.x] + sG[3][threadIdx.x];
        atomicAdd(&Gg[threadIdx.x], g4);
        atomicAdd(&Cg[threadIdx.x], hist[threadIdx.x]);
    }
}

// ---------------- l_aux finalize: one wave ----------------
__global__ void lauxfin(const float* __restrict__ Gg, const int* __restrict__ Cg,
                        float* __restrict__ out) {
    const int lane = threadIdx.x;  // 64 threads
    float v = Gg[lane] * (float)Cg[lane];
    #pragma unroll
    for (int o = 32; o; o >>= 1) v += __shfl_xor(v, o);
    // l_aux = sum_e G_e*C_e / (S*S) * (E*E/num_2nd) = sum/65536
    if (lane == 0) out[0] = v * (1.0f / 65536.0f);
}

// ---------------- rank + scatter: block per row ----------------
__global__ __launch_bounds__(256) void scatterk(const int* __restrict__ eidx, const float* __restrict__ gval,
                                                float* __restrict__ out) {
    const int s = blockIdx.x;
    const int my = eidx[s];
    int cnt = 0;
    for (int j = threadIdx.x; j < s; j += 256) cnt += (eidx[j] == my);
    __shared__ int sc[4];
    #pragma unroll
    for (int o = 32; o; o >>= 1) cnt += __shfl_down(cnt, o);
    const int wid = threadIdx.x >> 6, lane = threadIdx.x & 63;
    if (lane == 0) sc[wid] = cnt;
    __syncthreads();
    if (threadIdx.x == 0) {
        int rank = sc[0] + sc[1] + sc[2] + sc[3];   // = locations1_s
        if (rank < CAP) {
            size_t base = 1 + (((size_t)s * NE + my) * CAP + (size_t)rank);
            out[base] = gval[s];                                  // combine
            out[base + (size_t)S_ROWS * NE * CAP] = 1.0f;         // dispatch
        }
    }
}

extern "C" void kernel_launch(void* const* d_in, const int* in_sizes, int n_in,
                              void* d_out, int out_size, void* d_ws, size_t ws_size,
                              hipStream_t stream) {
    const float* in1 = (const float*)d_in[0];
    const float* in2 = (const float*)d_in[1];
    const float* wg1 = (const float*)d_in[2];
    const float* wg2 = (const float*)d_in[3];
    float* out = (float*)d_out;

    float* L1   = (float*)d_ws;                         // [S,64]
    float* L2   = L1 + (size_t)S_ROWS * NE;             // [S,64]
    int*   eidx = (int*)(L2 + (size_t)S_ROWS * NE);     // [S]
    float* gv   = (float*)(eidx + S_ROWS);              // [S]
    float* Gg   = gv + S_ROWS;                          // [64]
    int*   Cg   = (int*)(Gg + NE);                      // [64]

    long long n  = (long long)out_size;
    long long n4 = n >> 2;
    zerofill<<<4096, 256, 0, stream>>>((v4f*)out, n4, out, n);

    dim3 g(128, 2);
    gemm64<<<g, 256, 0, stream>>>(in1, wg1, in2, wg2, L1, L2, Gg, Cg);
    gatek2<<<S_ROWS / 16, 256, 0, stream>>>(L1, L2, eidx, gv, Gg, Cg);
    lauxfin<<<1, 64, 0, stream>>>(Gg, Cg, out);
    scatterk<<<S_ROWS, 256, 0, stream>>>(eidx, gv, out);
}

// Round 4
// 1075.387 us; speedup vs baseline: 1.1018x; 1.1018x over previous
//
#include <hip/hip_runtime.h>
#include <cstdint>
#include <cstddef>

#define S_ROWS 4096
#define DIM 1024
#define NE 64
#define CAP 512
#define NEGV -1e9f
#define NGEMM 128           // fused gemm+gating blocks, 32 rows each
#define NFILL 4096          // zero-fill blocks

typedef float v4f __attribute__((ext_vector_type(4)));

// ---------------- kernel A: zero-fill (blocks >= NGEMM) + fused gemm+gating (blocks < NGEMM) ----
__global__ __launch_bounds__(256) void fusedA(const float* __restrict__ X1, const float* __restrict__ W1,
                                              const float* __restrict__ X2, const float* __restrict__ W2,
                                              int* __restrict__ eidx, float* __restrict__ gval,
                                              float* __restrict__ Gslot, int* __restrict__ Cslot,
                                              v4f* __restrict__ out4, long long n4,
                                              float* __restrict__ out, long long n) {
    const int bid = blockIdx.x;
    const int tid = threadIdx.x;

    __shared__ float As[32][68];      // [row][k], +4 pad
    __shared__ float Bs[64][68];      // [k][expert]
    __shared__ float Lg[2][32][68];   // logits of both matrices, block-local rows
    __shared__ float sG[4][NE];
    __shared__ int   hist[NE];

    if (bid >= NGEMM) {
        // ---- streaming zero-fill of d_out (structural 1.07 GB write) ----
        long long i = (long long)(bid - NGEMM) * 256 + tid;
        const long long stride = (long long)(gridDim.x - NGEMM) * 256;
        v4f z = {0.f, 0.f, 0.f, 0.f};
        for (; i < n4; i += stride) __builtin_nontemporal_store(z, &out4[i]);
        if (bid == NGEMM && tid == 0)
            for (long long j = n4 * 4; j < n; ++j) out[j] = 0.f;   // 1 tail element
        return;
    }

    // ---- fused gemm (both matrices) + gating for rows [bid*32, bid*32+32) ----
    if (tid < NE) hist[tid] = 0;

    const int row0 = bid * 32;
    const int tx = tid & 15;          // expert quad
    const int ty = tid >> 4;          // row pair

    #pragma unroll
    for (int m = 0; m < 2; ++m) {
        const float* __restrict__ X = m ? X2 : X1;
        const float* __restrict__ W = m ? W2 : W1;
        float acc[2][4] = {};
        for (int kk = 0; kk < DIM; kk += 64) {
            __syncthreads();
            #pragma unroll
            for (int p = 0; p < 2; ++p) {
                int r  = ty + p * 16;
                int c4 = tx * 4;
                float4 a = *(const float4*)&X[(size_t)(row0 + r) * DIM + kk + c4];
                *(float4*)&As[r][c4] = a;
            }
            #pragma unroll
            for (int p = 0; p < 4; ++p) {
                int e  = ty + p * 16;
                int c4 = tx * 4;
                float4 w = *(const float4*)&W[(size_t)e * DIM + kk + c4];
                Bs[c4 + 0][e] = w.x;
                Bs[c4 + 1][e] = w.y;
                Bs[c4 + 2][e] = w.z;
                Bs[c4 + 3][e] = w.w;
            }
            __syncthreads();
            #pragma unroll
            for (int k4 = 0; k4 < 64; k4 += 4) {
                float4 a[2], b[4];
                #pragma unroll
                for (int i = 0; i < 2; ++i) a[i] = *(float4*)&As[ty * 2 + i][k4];
                #pragma unroll
                for (int t = 0; t < 4; ++t) b[t] = *(float4*)&Bs[k4 + t][tx * 4];
                #pragma unroll
                for (int i = 0; i < 2; ++i) {
                    acc[i][0] += a[i].x * b[0].x + a[i].y * b[1].x + a[i].z * b[2].x + a[i].w * b[3].x;
                    acc[i][1] += a[i].x * b[0].y + a[i].y * b[1].y + a[i].z * b[2].y + a[i].w * b[3].y;
                    acc[i][2] += a[i].x * b[0].z + a[i].y * b[1].z + a[i].z * b[2].z + a[i].w * b[3].z;
                    acc[i][3] += a[i].x * b[0].w + a[i].y * b[1].w + a[i].z * b[2].w + a[i].w * b[3].w;
                }
            }
        }
        #pragma unroll
        for (int i = 0; i < 2; ++i)
            #pragma unroll
            for (int t = 0; t < 4; ++t)
                Lg[m][ty * 2 + i][tx * 4 + t] = acc[i][t];
    }
    __syncthreads();   // logits of both matrices visible; hist init visible

    // gating: wave w handles local rows w*8 .. w*8+7 ; lane = expert
    const int wid = tid >> 6, lane = tid & 63;
    float gacc = 0.f;
    #pragma unroll
    for (int i = 0; i < 8; ++i) {
        const int lr = wid * 8 + i;
        const int r  = row0 + lr;
        float l1 = Lg[0][lr][lane];
        if (lane == 0) l1 = NEGV;                 // group 0 excluded before softmax

        // rank under (value desc, index asc) -> top-16 set == jax.lax.top_k set
        int cnt = 0;
        #pragma unroll
        for (int j = 0; j < 64; ++j) {
            float vj = __shfl(l1, j);
            cnt += (vj > l1 || (vj == l1 && j < lane));
        }
        const bool sel = cnt < 16;

        float l2 = Lg[1][lr][lane];
        float ml = sel ? l2 : NEGV;

        float mx = ml;
        #pragma unroll
        for (int o = 32; o; o >>= 1) mx = fmaxf(mx, __shfl_xor(mx, o));
        float ex = expf(ml - mx);                 // unselected underflow to exact 0
        float sum = ex;
        #pragma unroll
        for (int o = 32; o; o >>= 1) sum += __shfl_xor(sum, o);
        float g = ex / sum;
        gacc += g;

        // argmax, lowest-index tie-break (softmax monotone -> matches ref)
        float bg = g; int bi = lane;
        #pragma unroll
        for (int o = 32; o; o >>= 1) {
            float og = __shfl_xor(bg, o);
            int   oi = __shfl_xor(bi, o);
            if (og > bg || (og == bg && oi < bi)) { bg = og; bi = oi; }
        }
        if (lane == 0) {
            eidx[r] = bi;
            gval[r] = bg;
            atomicAdd(&hist[bi], 1);
        }
    }
    sG[wid][lane] = gacc;
    __syncthreads();
    if (tid < NE) {
        Gslot[bid * NE + tid] = sG[0][tid] + sG[1][tid] + sG[2][tid] + sG[3][tid];
        Cslot[bid * NE + tid] = hist[tid];
    }
}

// ---------------- kernel B: rank+scatter (blocks 0..4095) + l_aux reduce (block 4096) ----------
__global__ __launch_bounds__(256) void finishB(const int* __restrict__ eidx, const float* __restrict__ gval,
                                               const float* __restrict__ Gslot, const int* __restrict__ Cslot,
                                               float* __restrict__ out) {
    const int s = blockIdx.x;
    if (s == S_ROWS) {
        if (threadIdx.x < NE) {
            const int e = threadIdx.x;
            float Ge = 0.f; int Ce = 0;
            for (int b = 0; b < NGEMM; ++b) {
                Ge += Gslot[b * NE + e];
                Ce += Cslot[b * NE + e];
            }
            float v = Ge * (float)Ce;
            #pragma unroll
            for (int o = 32; o; o >>= 1) v += __shfl_xor(v, o);
            // l_aux = sum_e G_e*C_e / (S*S) * (E*E/num_2nd) = sum/65536
            if (e == 0) out[0] = v * (1.0f / 65536.0f);
        }
        return;
    }
    const int my = eidx[s];
    int cnt = 0;
    for (int j = threadIdx.x; j < s; j += 256) cnt += (eidx[j] == my);
    __shared__ int sc[4];
    #pragma unroll
    for (int o = 32; o; o >>= 1) cnt += __shfl_down(cnt, o);
    const int wid = threadIdx.x >> 6, lane = threadIdx.x & 63;
    if (lane == 0) sc[wid] = cnt;
    __syncthreads();
    if (threadIdx.x == 0) {
        int rank = sc[0] + sc[1] + sc[2] + sc[3];   // = locations1_s
        if (rank < CAP) {
            size_t base = 1 + (((size_t)s * NE + my) * CAP + (size_t)rank);
            out[base] = gval[s];                                  // combine
            out[base + (size_t)S_ROWS * NE * CAP] = 1.0f;         // dispatch
        }
    }
}

extern "C" void kernel_launch(void* const* d_in, const int* in_sizes, int n_in,
                              void* d_out, int out_size, void* d_ws, size_t ws_size,
                              hipStream_t stream) {
    const float* in1 = (const float*)d_in[0];
    const float* in2 = (const float*)d_in[1];
    const float* wg1 = (const float*)d_in[2];
    const float* wg2 = (const float*)d_in[3];
    float* out = (float*)d_out;

    int*   eidx  = (int*)d_ws;                          // [4096]
    float* gv    = (float*)(eidx + S_ROWS);             // [4096]
    float* Gslot = gv + S_ROWS;                         // [128*64]
    int*   Cslot = (int*)(Gslot + NGEMM * NE);          // [128*64]

    long long n  = (long long)out_size;
    long long n4 = n >> 2;

    fusedA<<<NGEMM + NFILL, 256, 0, stream>>>(in1, wg1, in2, wg2,
                                              eidx, gv, Gslot, Cslot,
                                              (v4f*)out, n4, out, n);
    finishB<<<S_ROWS + 1, 256, 0, stream>>>(eidx, gv, Gslot, Cslot, out);
}